// Round 12
// baseline (243.135 us; speedup 1.0000x reference)
//
#include <hip/hip_runtime.h>
#include <stdint.h>

#define N_NODES 100000
#define N_EDGES 25000
#define NNZ_    800000
#define D       256
#define NTOT    (N_EDGES + N_NODES)
#define MP      25024                 // N_EDGES padded to 64

// bucketed CSR build
#define SHE   9                       // edge keys per bucket = 512
#define SHV   11                      // node keys per bucket = 2048
#define WKE   512
#define WKV   2048
#define NBKE  ((N_EDGES + WKE - 1) / WKE)   // 49
#define NBKV  ((N_NODES + WKV - 1) / WKV)   // 49
#define NB    (NBKE + NBKV)                 // 98
#define CAP   24576                   // pairs capacity per bucket (mean 16384)

#define SC1B ((NNZ_ / 16 + 255) / 256)      // 196 scatter blocks (16 items/thread)
#define WB 256                              // cvt_wt blocks
#define CB ((N_NODES * D / 8 + 255) / 256)  // cvt_in blocks

typedef short  short8   __attribute__((ext_vector_type(8)));
typedef float  f32x4    __attribute__((ext_vector_type(4)));
typedef ushort ushortx8 __attribute__((ext_vector_type(8)));
typedef ushort ushortx4 __attribute__((ext_vector_type(4)));

__device__ __forceinline__ ushort f2bf(float f) {
    uint32_t u = __float_as_uint(f);
    uint32_t r = u + 0x7fffu + ((u >> 16) & 1u);
    return (ushort)(r >> 16);
}
__device__ __forceinline__ float bf2f(ushort u) {
    return __uint_as_float(((uint32_t)u) << 16);
}

// ---------------- zero the bucket cursors (replaces pathological hipMemsetAsync) ----------------

__global__ void zero_gcur(int* __restrict__ gcur) {
    gcur[threadIdx.x] = 0;
}

// ---------------- fused front: scatter1 (critical path, first) + cvt_wt + cvt_in ----------------

__global__ void __launch_bounds__(256) front_kernel(const int* __restrict__ V,
                                                    const int* __restrict__ E,
                                                    int* __restrict__ gcur,
                                                    int2* __restrict__ pairs,
                                                    const float* __restrict__ W,
                                                    ushort* __restrict__ WT,
                                                    const float* __restrict__ in,
                                                    ushort* __restrict__ Xbf) {
    __shared__ int cnt[NB], base[NB], lcur[NB];
    int b = blockIdx.x, t = threadIdx.x;
    if (b < SC1B) {
        for (int j = t; j < NB; j += 256) cnt[j] = 0;
        __syncthreads();
        int i0 = (b * 256 + t) * 16;
        bool act = i0 < NNZ_;
        if (act) {
#pragma unroll
            for (int c = 0; c < 16; c += 4) {
                int4 e = *reinterpret_cast<const int4*>(E + i0 + c);
                int4 v = *reinterpret_cast<const int4*>(V + i0 + c);
                atomicAdd(&cnt[e.x >> SHE], 1);
                atomicAdd(&cnt[e.y >> SHE], 1);
                atomicAdd(&cnt[e.z >> SHE], 1);
                atomicAdd(&cnt[e.w >> SHE], 1);
                atomicAdd(&cnt[NBKE + (v.x >> SHV)], 1);
                atomicAdd(&cnt[NBKE + (v.y >> SHV)], 1);
                atomicAdd(&cnt[NBKE + (v.z >> SHV)], 1);
                atomicAdd(&cnt[NBKE + (v.w >> SHV)], 1);
            }
        }
        __syncthreads();
        for (int j = t; j < NB; j += 256) {
            int c = cnt[j];
            base[j] = c ? atomicAdd(&gcur[j], c) : 0;
            lcur[j] = 0;
        }
        __syncthreads();
        if (act) {
#pragma unroll
            for (int c = 0; c < 16; c += 4) {
                int4 e = *reinterpret_cast<const int4*>(E + i0 + c);
                int4 v = *reinterpret_cast<const int4*>(V + i0 + c);
                int ev[4] = {e.x, e.y, e.z, e.w};
                int vv[4] = {v.x, v.y, v.z, v.w};
#pragma unroll
                for (int k = 0; k < 4; ++k) {
                    int b1 = ev[k] >> SHE;
                    int p1 = base[b1] + atomicAdd(&lcur[b1], 1);
                    if (p1 < CAP) pairs[(size_t)b1 * CAP + p1] = make_int2(ev[k], vv[k]);
                    int b2 = NBKE + (vv[k] >> SHV);
                    int p2 = base[b2] + atomicAdd(&lcur[b2], 1);
                    if (p2 < CAP) pairs[(size_t)b2 * CAP + p2] = make_int2(vv[k], ev[k]);
                }
            }
        }
    } else if (b < SC1B + WB) {
        int g = (b - SC1B) * 256 + t;
        int n = g >> 8, k = g & 255;
        WT[(size_t)n * 256 + k] = f2bf(W[(size_t)k * 256 + n]);
    } else {
        int i = (b - SC1B - WB) * 256 + t;
        if (i >= N_NODES * D / 8) return;
        const f32x4* p = reinterpret_cast<const f32x4*>(in) + (size_t)i * 2;
        f32x4 a = __builtin_nontemporal_load(p);
        f32x4 c = __builtin_nontemporal_load(p + 1);
        ushortx8 o;
        o[0] = f2bf(a[0]); o[1] = f2bf(a[1]); o[2] = f2bf(a[2]); o[3] = f2bf(a[3]);
        o[4] = f2bf(c[0]); o[5] = f2bf(c[1]); o[6] = f2bf(c[2]); o[7] = f2bf(c[3]);
        *(reinterpret_cast<ushortx8*>(Xbf) + i) = o;
    }
}

// ---------------- fused CSR build: hist + local scan + offC + fill (one block per bucket) ----------------

__global__ void __launch_bounds__(256) build_csr(const int2* __restrict__ pairs,
                                                 const int* __restrict__ gcur,
                                                 int* __restrict__ offC,
                                                 int* __restrict__ adjAll) {
    __shared__ int hist[WKV];          // 2048 (edge buckets use first 512; rest stay 0)
    __shared__ int tsum[256];
    __shared__ int bsum_sh[NB];
    __shared__ int bbase_sh;
    int b = blockIdx.x, t = threadIdx.x;
    bool eside = b < NBKE;
    int kb    = eside ? b * WKE : (b - NBKE) * WKV;
    int nk    = eside ? min(WKE, N_EDGES - kb) : min(WKV, N_NODES - kb);
    int obase = eside ? kb : N_EDGES + kb;
    for (int j = t; j < WKV; j += 256) hist[j] = 0;
    if (t < NB) bsum_sh[t] = gcur[t];
    __syncthreads();
    if (t == 0) {
        int s = 0;
        for (int j = 0; j < b; ++j) s += bsum_sh[j];
        bbase_sh = s;
    }
    int n = min(gcur[b], CAP);
    const int2* p = pairs + (size_t)b * CAP;
    for (int i = t; i < n; i += 256) {
        atomicAdd(&hist[p[i].x - kb], 1);
    }
    __syncthreads();
    int bbase = bbase_sh;
    int j0 = t * 8;
    int s = 0;
#pragma unroll
    for (int j = 0; j < 8; ++j) s += hist[j0 + j];
    tsum[t] = s;
    __syncthreads();
    for (int o = 1; o < 256; o <<= 1) {
        int u = (t >= o) ? tsum[t - o] : 0;
        __syncthreads();
        tsum[t] += u;
        __syncthreads();
    }
    int excl = tsum[t] - s;
    int curv[8];
#pragma unroll
    for (int j = 0; j < 8; ++j) {
        int h = hist[j0 + j];
        curv[j] = bbase + excl;
        if (j0 + j < nk) offC[obase + j0 + j] = bbase + excl;
        excl += h;
    }
    __syncthreads();
#pragma unroll
    for (int j = 0; j < 8; ++j) hist[j0 + j] = curv[j];   // global cursor
    if (b == NB - 1 && t == 0) offC[NTOT] = bbase + n;
    __syncthreads();
    for (int i = t; i < n; i += 256) {
        int2 pr = p[i];
        int slot = atomicAdd(&hist[pr.x - kb], 1);
        adjAll[slot] = pr.y;
    }
}

// ---------------- shared gather core: lane-parallel index prefetch + shuffle broadcast ----------------

__device__ __forceinline__ void gather_rows(const ushort* __restrict__ src,
                                            const int* __restrict__ adjAll,
                                            int b, int cnt, int half, int col8,
                                            float a[8], int lane) {
    for (int c0 = 0; c0 < cnt; c0 += 64) {
        int rem = cnt - c0;                        // > 0
        int li = c0 + min(lane, rem - 1);
        int myidx = adjAll[b + li];                // one coalesced load per chunk
        int lim = min(rem, 64);
        for (int j0 = 0; j0 < lim; j0 += 8) {
            int r0 = __shfl(myidx, j0 + 0 + half, 64);
            int r1 = __shfl(myidx, j0 + 2 + half, 64);
            int r2 = __shfl(myidx, j0 + 4 + half, 64);
            int r3 = __shfl(myidx, j0 + 6 + half, 64);
            ushortx8 x0 = *reinterpret_cast<const ushortx8*>(src + (size_t)r0 * D + col8);
            ushortx8 x1 = *reinterpret_cast<const ushortx8*>(src + (size_t)r1 * D + col8);
            ushortx8 x2 = *reinterpret_cast<const ushortx8*>(src + (size_t)r2 * D + col8);
            ushortx8 x3 = *reinterpret_cast<const ushortx8*>(src + (size_t)r3 * D + col8);
            if (j0 + 0 + half < lim) {
#pragma unroll
                for (int k = 0; k < 8; ++k) a[k] += bf2f(x0[k]);
            }
            if (j0 + 2 + half < lim) {
#pragma unroll
                for (int k = 0; k < 8; ++k) a[k] += bf2f(x1[k]);
            }
            if (j0 + 4 + half < lim) {
#pragma unroll
                for (int k = 0; k < 8; ++k) a[k] += bf2f(x2[k]);
            }
            if (j0 + 6 + half < lim) {
#pragma unroll
                for (int k = 0; k < 8; ++k) a[k] += bf2f(x3[k]);
            }
        }
    }
}

// ---------------- phase 1: edge aggregation (one wave per edge) ----------------

__global__ void edge_agg(const ushort* __restrict__ Xbf, const int* __restrict__ adjAll,
                         const int* __restrict__ offC, const float* __restrict__ degE,
                         ushort* __restrict__ Ye) {
    int gid = blockIdx.x * blockDim.x + threadIdx.x;
    int edge = gid >> 6;
    int lane = gid & 63;
    if (edge >= N_EDGES) return;
    int half = lane >> 5;
    int col8 = (lane & 31) * 8;
    int b = offC[edge], e = offC[edge + 1];
    int cnt = e - b;
    float a[8] = {0.f, 0.f, 0.f, 0.f, 0.f, 0.f, 0.f, 0.f};
    gather_rows(Xbf, adjAll, b, cnt, half, col8, a, lane);
#pragma unroll
    for (int k = 0; k < 8; ++k) a[k] += __shfl_xor(a[k], 32, 64);
    float s = degE[edge] / (float)(cnt > 1 ? cnt : 1);
    int k0 = half * 4;
    ushortx4 o;
    o[0] = f2bf(a[k0 + 0] * s); o[1] = f2bf(a[k0 + 1] * s);
    o[2] = f2bf(a[k0 + 2] * s); o[3] = f2bf(a[k0 + 3] * s);
    *reinterpret_cast<ushortx4*>(Ye + (size_t)edge * D + col8 + k0) = o;
}

// ---------------- phase 2: MFMA GEMM  Ze[MP,256] = Ye[MP,256] @ W  (bf16, LDS-free) ----------------

__global__ void __launch_bounds__(256) gemm_mfma(const ushort* __restrict__ A,
                                                 const ushort* __restrict__ WT,
                                                 ushort* __restrict__ C, int M) {
    int wid  = threadIdx.x >> 6;
    int lane = threadIdx.x & 63;
    int row0 = blockIdx.x * 64 + wid * 16;
    int lr  = lane & 15;
    int lk8 = (lane >> 4) * 8;
    f32x4 acc[16];
#pragma unroll
    for (int t = 0; t < 16; ++t) acc[t] = (f32x4){0.f, 0.f, 0.f, 0.f};
    int arow = row0 + lr;
    if (arow >= M) arow = M - 1;
    const ushort* aptr = A + (size_t)arow * D;
#pragma unroll
    for (int k0 = 0; k0 < D; k0 += 32) {
        short8 af = *reinterpret_cast<const short8*>(aptr + k0 + lk8);
#pragma unroll
        for (int t = 0; t < 16; ++t) {
            short8 bf = *reinterpret_cast<const short8*>(
                WT + (size_t)(t * 16 + lr) * D + k0 + lk8);
            acc[t] = __builtin_amdgcn_mfma_f32_16x16x32_bf16(af, bf, acc[t], 0, 0, 0);
        }
    }
    int crow = row0 + (lane >> 4) * 4;
#pragma unroll
    for (int t = 0; t < 16; ++t) {
        int ccol = t * 16 + lr;
#pragma unroll
        for (int r = 0; r < 4; ++r) {
            int rr = crow + r;
            if (rr < M) C[(size_t)rr * D + ccol] = f2bf(acc[t][r]);
        }
    }
}

// ---------------- phase 3: node aggregation (one wave per node, NT store) ----------------

__global__ void node_agg(const ushort* __restrict__ Ze, const int* __restrict__ adjAll,
                         const int* __restrict__ offC, const float* __restrict__ degV,
                         const float* __restrict__ bias, float* __restrict__ out) {
    int gid = blockIdx.x * blockDim.x + threadIdx.x;
    int node = gid >> 6;
    int lane = gid & 63;
    if (node >= N_NODES) return;
    int half = lane >> 5;
    int col8 = (lane & 31) * 8;
    int b = offC[N_EDGES + node], e = offC[N_EDGES + node + 1];
    int cnt = e - b;
    float a[8] = {0.f, 0.f, 0.f, 0.f, 0.f, 0.f, 0.f, 0.f};
    gather_rows(Ze, adjAll, b, cnt, half, col8, a, lane);
#pragma unroll
    for (int k = 0; k < 8; ++k) a[k] += __shfl_xor(a[k], 32, 64);
    float dv = degV[node];
    int k0 = half * 4;
    int c = col8 + k0;
    f32x4 b4 = *reinterpret_cast<const f32x4*>(bias + c);
    f32x4 o;
    o[0] = a[k0 + 0] * dv + b4[0];
    o[1] = a[k0 + 1] * dv + b4[1];
    o[2] = a[k0 + 2] * dv + b4[2];
    o[3] = a[k0 + 3] * dv + b4[3];
    __builtin_nontemporal_store(o, reinterpret_cast<f32x4*>(out + (size_t)node * D + c));
}

// ---------------- launch ----------------

extern "C" void kernel_launch(void* const* d_in, const int* in_sizes, int n_in,
                              void* d_out, int out_size, void* d_ws, size_t ws_size,
                              hipStream_t stream) {
    const float* input  = (const float*)d_in[0];
    const int*   V      = (const int*)d_in[1];
    const int*   E      = (const int*)d_in[2];
    const float* degV   = (const float*)d_in[3];
    const float* degE   = (const float*)d_in[4];
    const float* weight = (const float*)d_in[5];
    const float* bias   = (const float*)d_in[6];
    float* out = (float*)d_out;

    int* gcur   = (int*)d_ws;                       // 128 (98 used)
    int* offC   = gcur + 128;                       // NTOT+1
    int* adjAll = offC + (NTOT + 1);                // 2*NNZ
    uintptr_t p = (uintptr_t)(adjAll + 2 * NNZ_);
    p = (p + 255) & ~(uintptr_t)255;
    ushort* Xbf = (ushort*)p;                       // N_NODES*D   (51.2 MB)
    ushort* Ye  = Xbf + (size_t)N_NODES * D;        // MP*D        (12.8 MB)
    ushort* Ze  = Ye + (size_t)MP * D;              // MP*D        (12.8 MB)
    ushort* WT  = Ze + (size_t)MP * D;              // 256*256     (128 KB)
    int2* pairs = (int2*)Ye;                        // 19.3MB, aliases Ye+Ze (dead until edge_agg)

    zero_gcur<<<1, 128, 0, stream>>>(gcur);

    front_kernel<<<SC1B + WB + CB, 256, 0, stream>>>(V, E, gcur, pairs,
                                                     weight, WT, input, Xbf);

    build_csr<<<NB, 256, 0, stream>>>(pairs, gcur, offC, adjAll);

    edge_agg<<<(N_EDGES * 64 + 255) / 256, 256, 0, stream>>>(Xbf, adjAll, offC, degE, Ye);

    gemm_mfma<<<MP / 64, 256, 0, stream>>>(Ye, WT, Ze, N_EDGES);

    node_agg<<<(N_NODES * 64 + 255) / 256, 256, 0, stream>>>(Ze, adjAll, offC, degV, bias, out);
}

// Round 13
// 240.728 us; speedup vs baseline: 1.0100x; 1.0100x over previous
//
#include <hip/hip_runtime.h>
#include <stdint.h>

#define N_NODES 100000
#define N_EDGES 25000
#define NNZ_    800000
#define D       256
#define NTOT    (N_EDGES + N_NODES)
#define MP      25024                 // N_EDGES padded to 64

// bucketed CSR build
#define SHE   9                       // edge keys per bucket = 512
#define SHV   11                      // node keys per bucket = 2048
#define WKE   512
#define WKV   2048
#define NBKE  ((N_EDGES + WKE - 1) / WKE)   // 49
#define NBKV  ((N_NODES + WKV - 1) / WKV)   // 49
#define NB    (NBKE + NBKV)                 // 98
#define CAP   24576                   // pairs capacity per bucket (mean 16384)

#define SC1B ((NNZ_ / 16 + 255) / 256)      // 196 scatter blocks (16 items/thread)
#define WB 256                              // cvt_wt blocks
#define CB ((N_NODES * D / 8 + 255) / 256)  // cvt_in blocks

typedef short  short8   __attribute__((ext_vector_type(8)));
typedef float  f32x4    __attribute__((ext_vector_type(4)));
typedef ushort ushortx8 __attribute__((ext_vector_type(8)));
typedef ushort ushortx4 __attribute__((ext_vector_type(4)));

__device__ __forceinline__ ushort f2bf(float f) {
    uint32_t u = __float_as_uint(f);
    uint32_t r = u + 0x7fffu + ((u >> 16) & 1u);
    return (ushort)(r >> 16);
}
__device__ __forceinline__ float bf2f(ushort u) {
    return __uint_as_float(((uint32_t)u) << 16);
}

// ---------------- zero the bucket cursors ----------------

__global__ void zero_gcur(int* __restrict__ gcur) {
    gcur[threadIdx.x] = 0;
}

// ---------------- fused front: scatter1 + cvt_wt + cvt_in ----------------

__global__ void __launch_bounds__(256) front_kernel(const int* __restrict__ V,
                                                    const int* __restrict__ E,
                                                    int* __restrict__ gcur,
                                                    int2* __restrict__ pairs,
                                                    const float* __restrict__ W,
                                                    ushort* __restrict__ WT,
                                                    const float* __restrict__ in,
                                                    ushort* __restrict__ Xbf) {
    __shared__ int cnt[NB], base[NB], lcur[NB];
    int b = blockIdx.x, t = threadIdx.x;
    if (b < SC1B) {
        for (int j = t; j < NB; j += 256) cnt[j] = 0;
        __syncthreads();
        int i0 = (b * 256 + t) * 16;
        bool act = i0 < NNZ_;
        if (act) {
#pragma unroll
            for (int c = 0; c < 16; c += 4) {
                int4 e = *reinterpret_cast<const int4*>(E + i0 + c);
                int4 v = *reinterpret_cast<const int4*>(V + i0 + c);
                atomicAdd(&cnt[e.x >> SHE], 1);
                atomicAdd(&cnt[e.y >> SHE], 1);
                atomicAdd(&cnt[e.z >> SHE], 1);
                atomicAdd(&cnt[e.w >> SHE], 1);
                atomicAdd(&cnt[NBKE + (v.x >> SHV)], 1);
                atomicAdd(&cnt[NBKE + (v.y >> SHV)], 1);
                atomicAdd(&cnt[NBKE + (v.z >> SHV)], 1);
                atomicAdd(&cnt[NBKE + (v.w >> SHV)], 1);
            }
        }
        __syncthreads();
        for (int j = t; j < NB; j += 256) {
            int c = cnt[j];
            base[j] = c ? atomicAdd(&gcur[j], c) : 0;
            lcur[j] = 0;
        }
        __syncthreads();
        if (act) {
#pragma unroll
            for (int c = 0; c < 16; c += 4) {
                int4 e = *reinterpret_cast<const int4*>(E + i0 + c);
                int4 v = *reinterpret_cast<const int4*>(V + i0 + c);
                int ev[4] = {e.x, e.y, e.z, e.w};
                int vv[4] = {v.x, v.y, v.z, v.w};
#pragma unroll
                for (int k = 0; k < 4; ++k) {
                    int b1 = ev[k] >> SHE;
                    int p1 = base[b1] + atomicAdd(&lcur[b1], 1);
                    if (p1 < CAP) pairs[(size_t)b1 * CAP + p1] = make_int2(ev[k], vv[k]);
                    int b2 = NBKE + (vv[k] >> SHV);
                    int p2 = base[b2] + atomicAdd(&lcur[b2], 1);
                    if (p2 < CAP) pairs[(size_t)b2 * CAP + p2] = make_int2(vv[k], ev[k]);
                }
            }
        }
    } else if (b < SC1B + WB) {
        int g = (b - SC1B) * 256 + t;
        int n = g >> 8, k = g & 255;
        WT[(size_t)n * 256 + k] = f2bf(W[(size_t)k * 256 + n]);
    } else {
        int i = (b - SC1B - WB) * 256 + t;
        if (i >= N_NODES * D / 8) return;
        const f32x4* p = reinterpret_cast<const f32x4*>(in) + (size_t)i * 2;
        f32x4 a = __builtin_nontemporal_load(p);
        f32x4 c = __builtin_nontemporal_load(p + 1);
        ushortx8 o;
        o[0] = f2bf(a[0]); o[1] = f2bf(a[1]); o[2] = f2bf(a[2]); o[3] = f2bf(a[3]);
        o[4] = f2bf(c[0]); o[5] = f2bf(c[1]); o[6] = f2bf(c[2]); o[7] = f2bf(c[3]);
        *(reinterpret_cast<ushortx8*>(Xbf) + i) = o;
    }
}

// ---------------- fused CSR build ----------------

__global__ void __launch_bounds__(256) build_csr(const int2* __restrict__ pairs,
                                                 const int* __restrict__ gcur,
                                                 int* __restrict__ offC,
                                                 int* __restrict__ adjAll) {
    __shared__ int hist[WKV];
    __shared__ int tsum[256];
    __shared__ int bsum_sh[NB];
    __shared__ int bbase_sh;
    int b = blockIdx.x, t = threadIdx.x;
    bool eside = b < NBKE;
    int kb    = eside ? b * WKE : (b - NBKE) * WKV;
    int nk    = eside ? min(WKE, N_EDGES - kb) : min(WKV, N_NODES - kb);
    int obase = eside ? kb : N_EDGES + kb;
    for (int j = t; j < WKV; j += 256) hist[j] = 0;
    if (t < NB) bsum_sh[t] = gcur[t];
    __syncthreads();
    if (t == 0) {
        int s = 0;
        for (int j = 0; j < b; ++j) s += bsum_sh[j];
        bbase_sh = s;
    }
    int n = min(gcur[b], CAP);
    const int2* p = pairs + (size_t)b * CAP;
    for (int i = t; i < n; i += 256) {
        atomicAdd(&hist[p[i].x - kb], 1);
    }
    __syncthreads();
    int bbase = bbase_sh;
    int j0 = t * 8;
    int s = 0;
#pragma unroll
    for (int j = 0; j < 8; ++j) s += hist[j0 + j];
    tsum[t] = s;
    __syncthreads();
    for (int o = 1; o < 256; o <<= 1) {
        int u = (t >= o) ? tsum[t - o] : 0;
        __syncthreads();
        tsum[t] += u;
        __syncthreads();
    }
    int excl = tsum[t] - s;
    int curv[8];
#pragma unroll
    for (int j = 0; j < 8; ++j) {
        int h = hist[j0 + j];
        curv[j] = bbase + excl;
        if (j0 + j < nk) offC[obase + j0 + j] = bbase + excl;
        excl += h;
    }
    __syncthreads();
#pragma unroll
    for (int j = 0; j < 8; ++j) hist[j0 + j] = curv[j];
    if (b == NB - 1 && t == 0) offC[NTOT] = bbase + n;
    __syncthreads();
    for (int i = t; i < n; i += 256) {
        int2 pr = p[i];
        int slot = atomicAdd(&hist[pr.x - kb], 1);
        adjAll[slot] = pr.y;
    }
}

// ---------------- phase 1: edge aggregation (quarter-wave/row, 2 column panels) ----------------
// Per panel (128 cols = 25.6MB working set): quarter q handles rows i+q; each lane
// reads 16B (8 cols). j0 += 16 keeps 4 independent row-loads in flight per lane.

__global__ void edge_agg(const ushort* __restrict__ Xbf, const int* __restrict__ adjAll,
                         const int* __restrict__ offC, const float* __restrict__ degE,
                         ushort* __restrict__ Ye) {
    int gid = blockIdx.x * blockDim.x + threadIdx.x;
    int edge = gid >> 6;
    int lane = gid & 63;
    if (edge >= N_EDGES) return;
    int q  = lane >> 4;               // quarter 0..3
    int c8 = (lane & 15) * 8;         // col offset within panel
    int b = offC[edge], e = offC[edge + 1];
    int cnt = e - b;
    float s = degE[edge] / (float)(cnt > 1 ? cnt : 1);
#pragma unroll
    for (int panel = 0; panel < 2; ++panel) {
        int pc = panel * 128 + c8;
        float a[8] = {0.f, 0.f, 0.f, 0.f, 0.f, 0.f, 0.f, 0.f};
        for (int c0 = 0; c0 < cnt; c0 += 64) {
            int rem = cnt - c0;
            int li = c0 + min(lane, rem - 1);
            int myidx = adjAll[b + li];
            int lim = min(rem, 64);
            for (int j0 = 0; j0 < lim; j0 += 16) {
                int r0 = __shfl(myidx, j0 + 0  + q, 64);
                int r1 = __shfl(myidx, j0 + 4  + q, 64);
                int r2 = __shfl(myidx, j0 + 8  + q, 64);
                int r3 = __shfl(myidx, j0 + 12 + q, 64);
                ushortx8 x0 = *reinterpret_cast<const ushortx8*>(Xbf + (size_t)r0 * D + pc);
                ushortx8 x1 = *reinterpret_cast<const ushortx8*>(Xbf + (size_t)r1 * D + pc);
                ushortx8 x2 = *reinterpret_cast<const ushortx8*>(Xbf + (size_t)r2 * D + pc);
                ushortx8 x3 = *reinterpret_cast<const ushortx8*>(Xbf + (size_t)r3 * D + pc);
                if (j0 + 0 + q < lim) {
#pragma unroll
                    for (int k = 0; k < 8; ++k) a[k] += bf2f(x0[k]);
                }
                if (j0 + 4 + q < lim) {
#pragma unroll
                    for (int k = 0; k < 8; ++k) a[k] += bf2f(x1[k]);
                }
                if (j0 + 8 + q < lim) {
#pragma unroll
                    for (int k = 0; k < 8; ++k) a[k] += bf2f(x2[k]);
                }
                if (j0 + 12 + q < lim) {
#pragma unroll
                    for (int k = 0; k < 8; ++k) a[k] += bf2f(x3[k]);
                }
            }
        }
#pragma unroll
        for (int k = 0; k < 8; ++k) {
            a[k] += __shfl_xor(a[k], 16, 64);
            a[k] += __shfl_xor(a[k], 32, 64);
        }
        if (q == 0) {
            ushortx8 o;
#pragma unroll
            for (int k = 0; k < 8; ++k) o[k] = f2bf(a[k] * s);
            *reinterpret_cast<ushortx8*>(Ye + (size_t)edge * D + pc) = o;
        }
    }
}

// ---------------- phase 2: MFMA GEMM  Ze[MP,256] = Ye[MP,256] @ W  (bf16, LDS-free) ----------------

__global__ void __launch_bounds__(256) gemm_mfma(const ushort* __restrict__ A,
                                                 const ushort* __restrict__ WT,
                                                 ushort* __restrict__ C, int M) {
    int wid  = threadIdx.x >> 6;
    int lane = threadIdx.x & 63;
    int row0 = blockIdx.x * 64 + wid * 16;
    int lr  = lane & 15;
    int lk8 = (lane >> 4) * 8;
    f32x4 acc[16];
#pragma unroll
    for (int t = 0; t < 16; ++t) acc[t] = (f32x4){0.f, 0.f, 0.f, 0.f};
    int arow = row0 + lr;
    if (arow >= M) arow = M - 1;
    const ushort* aptr = A + (size_t)arow * D;
#pragma unroll
    for (int k0 = 0; k0 < D; k0 += 32) {
        short8 af = *reinterpret_cast<const short8*>(aptr + k0 + lk8);
#pragma unroll
        for (int t = 0; t < 16; ++t) {
            short8 bf = *reinterpret_cast<const short8*>(
                WT + (size_t)(t * 16 + lr) * D + k0 + lk8);
            acc[t] = __builtin_amdgcn_mfma_f32_16x16x32_bf16(af, bf, acc[t], 0, 0, 0);
        }
    }
    int crow = row0 + (lane >> 4) * 4;
#pragma unroll
    for (int t = 0; t < 16; ++t) {
        int ccol = t * 16 + lr;
#pragma unroll
        for (int r = 0; r < 4; ++r) {
            int rr = crow + r;
            if (rr < M) C[(size_t)rr * D + ccol] = f2bf(acc[t][r]);
        }
    }
}

// ---------------- shared gather core (half-wave) for node side ----------------

__device__ __forceinline__ void gather_rows(const ushort* __restrict__ src,
                                            const int* __restrict__ adjAll,
                                            int b, int cnt, int half, int col8,
                                            float a[8], int lane) {
    for (int c0 = 0; c0 < cnt; c0 += 64) {
        int rem = cnt - c0;
        int li = c0 + min(lane, rem - 1);
        int myidx = adjAll[b + li];
        int lim = min(rem, 64);
        for (int j0 = 0; j0 < lim; j0 += 8) {
            int r0 = __shfl(myidx, j0 + 0 + half, 64);
            int r1 = __shfl(myidx, j0 + 2 + half, 64);
            int r2 = __shfl(myidx, j0 + 4 + half, 64);
            int r3 = __shfl(myidx, j0 + 6 + half, 64);
            ushortx8 x0 = *reinterpret_cast<const ushortx8*>(src + (size_t)r0 * D + col8);
            ushortx8 x1 = *reinterpret_cast<const ushortx8*>(src + (size_t)r1 * D + col8);
            ushortx8 x2 = *reinterpret_cast<const ushortx8*>(src + (size_t)r2 * D + col8);
            ushortx8 x3 = *reinterpret_cast<const ushortx8*>(src + (size_t)r3 * D + col8);
            if (j0 + 0 + half < lim) {
#pragma unroll
                for (int k = 0; k < 8; ++k) a[k] += bf2f(x0[k]);
            }
            if (j0 + 2 + half < lim) {
#pragma unroll
                for (int k = 0; k < 8; ++k) a[k] += bf2f(x1[k]);
            }
            if (j0 + 4 + half < lim) {
#pragma unroll
                for (int k = 0; k < 8; ++k) a[k] += bf2f(x2[k]);
            }
            if (j0 + 6 + half < lim) {
#pragma unroll
                for (int k = 0; k < 8; ++k) a[k] += bf2f(x3[k]);
            }
        }
    }
}

// ---------------- phase 3: node aggregation (one wave per node, NT store) ----------------

__global__ void node_agg(const ushort* __restrict__ Ze, const int* __restrict__ adjAll,
                         const int* __restrict__ offC, const float* __restrict__ degV,
                         const float* __restrict__ bias, float* __restrict__ out) {
    int gid = blockIdx.x * blockDim.x + threadIdx.x;
    int node = gid >> 6;
    int lane = gid & 63;
    if (node >= N_NODES) return;
    int half = lane >> 5;
    int col8 = (lane & 31) * 8;
    int b = offC[N_EDGES + node], e = offC[N_EDGES + node + 1];
    int cnt = e - b;
    float a[8] = {0.f, 0.f, 0.f, 0.f, 0.f, 0.f, 0.f, 0.f};
    gather_rows(Ze, adjAll, b, cnt, half, col8, a, lane);
#pragma unroll
    for (int k = 0; k < 8; ++k) a[k] += __shfl_xor(a[k], 32, 64);
    float dv = degV[node];
    int k0 = half * 4;
    int c = col8 + k0;
    f32x4 b4 = *reinterpret_cast<const f32x4*>(bias + c);
    f32x4 o;
    o[0] = a[k0 + 0] * dv + b4[0];
    o[1] = a[k0 + 1] * dv + b4[1];
    o[2] = a[k0 + 2] * dv + b4[2];
    o[3] = a[k0 + 3] * dv + b4[3];
    __builtin_nontemporal_store(o, reinterpret_cast<f32x4*>(out + (size_t)node * D + c));
}

// ---------------- launch ----------------

extern "C" void kernel_launch(void* const* d_in, const int* in_sizes, int n_in,
                              void* d_out, int out_size, void* d_ws, size_t ws_size,
                              hipStream_t stream) {
    const float* input  = (const float*)d_in[0];
    const int*   V      = (const int*)d_in[1];
    const int*   E      = (const int*)d_in[2];
    const float* degV   = (const float*)d_in[3];
    const float* degE   = (const float*)d_in[4];
    const float* weight = (const float*)d_in[5];
    const float* bias   = (const float*)d_in[6];
    float* out = (float*)d_out;

    int* gcur   = (int*)d_ws;                       // 128 (98 used)
    int* offC   = gcur + 128;                       // NTOT+1
    int* adjAll = offC + (NTOT + 1);                // 2*NNZ
    uintptr_t p = (uintptr_t)(adjAll + 2 * NNZ_);
    p = (p + 255) & ~(uintptr_t)255;
    ushort* Xbf = (ushort*)p;                       // N_NODES*D   (51.2 MB)
    ushort* Ye  = Xbf + (size_t)N_NODES * D;        // MP*D        (12.8 MB)
    ushort* Ze  = Ye + (size_t)MP * D;              // MP*D        (12.8 MB)
    ushort* WT  = Ze + (size_t)MP * D;              // 256*256     (128 KB)
    int2* pairs = (int2*)Ye;                        // 19.3MB, aliases Ye+Ze

    zero_gcur<<<1, 128, 0, stream>>>(gcur);

    front_kernel<<<SC1B + WB + CB, 256, 0, stream>>>(V, E, gcur, pairs,
                                                     weight, WT, input, Xbf);

    build_csr<<<NB, 256, 0, stream>>>(pairs, gcur, offC, adjAll);

    edge_agg<<<(N_EDGES * 64 + 255) / 256, 256, 0, stream>>>(Xbf, adjAll, offC, degE, Ye);

    gemm_mfma<<<MP / 64, 256, 0, stream>>>(Ye, WT, Ze, N_EDGES);

    node_agg<<<(N_NODES * 64 + 255) / 256, 256, 0, stream>>>(Ze, adjAll, offC, degV, bias, out);
}